// Round 11
// baseline (51857.098 us; speedup 1.0000x reference)
//
#include <hip/hip_runtime.h>
#include <hip/hip_bf16.h>

// Problem constants
#define BB 128   // batch
#define TT 1024  // timesteps
#define HH 512   // hidden
#define VV 256   // vocab
#define NBLK 256 // census grid: PURE uses XCD0-3 (32 blocks each); FALLBACK uses bids 0-127

typedef __attribute__((ext_vector_type(8))) short short8;   // 8 x bf16
typedef __attribute__((ext_vector_type(4))) float floatx4;  // MFMA acc

__device__ __forceinline__ floatx4 mfma16(short8 a, short8 b, floatx4 c) {
    return __builtin_amdgcn_mfma_f32_16x16x32_bf16(a, b, c, 0, 0, 0);
}
__device__ __forceinline__ float sigm(float x) { return 1.0f / (1.0f + __expf(-x)); }
__device__ __forceinline__ float tanh_fast(float x) {
    return 2.0f / (1.0f + __expf(-2.0f * x)) - 1.0f;
}
__device__ __forceinline__ void vmcnt0() {
    asm volatile("s_waitcnt vmcnt(0)" ::: "memory");
}
__device__ __forceinline__ void vm_fence() {
    asm volatile("s_waitcnt vmcnt(0)" ::: "memory");
    __builtin_amdgcn_sched_barrier(0);
}
__device__ __forceinline__ void cfence() {
    asm volatile("" ::: "memory");
    __builtin_amdgcn_sched_barrier(0);
}
// Agent-scope relaxed ops: MALL-coherent.
__device__ __forceinline__ unsigned ald32(const unsigned* p) {
    return __hip_atomic_load(p, __ATOMIC_RELAXED, __HIP_MEMORY_SCOPE_AGENT);
}
__device__ __forceinline__ void ast32(unsigned* p, unsigned v) {
    __hip_atomic_store(p, v, __ATOMIC_RELAXED, __HIP_MEMORY_SCOPE_AGENT);
}
__device__ __forceinline__ unsigned get_xcc() {
    unsigned x;
    asm("s_getreg_b32 %0, hwreg(HW_REG_XCC_ID)" : "=s"(x));
    return x & 7u;
}
// sc0 load: bypass per-CU L1, served by the XCD's own L2 (local-release consumer).
__device__ __forceinline__ unsigned ld32_sc0(const unsigned* p) {
    unsigned v;
    asm volatile("global_load_dword %0, %1, off sc0\n\ts_waitcnt vmcnt(0)"
                 : "=v"(v) : "v"(p) : "memory");
    return v;
}
__device__ __forceinline__ short8 ld16_sc0(const __hip_bfloat16* p) {
    short8 v;
    asm volatile("global_load_dwordx4 %0, %1, off sc0" : "=v"(v) : "v"(p));
    return v;
}
// MALL-path 16B load (bypasses local caches) for cross-XCD/reused addresses.
__device__ __forceinline__ short8 ld16_sc1(const __hip_bfloat16* p) {
    short8 v;
    asm volatile("global_load_dwordx4 %0, %1, off sc1" : "=v"(v) : "v"(p));
    return v;
}

// Unified watchdogged gate: all 32 words of the gate line >= tgt.
// locl!=null: fast sc0 poll of the XCD-local line, with MALL-mirror fail-soft
// sample every 256 iters (if sc0 semantics fail, we degrade, not deadlock).
// locl==null: poll mir (MALL) directly. Satisfied always wins over abort.
// Cap -> set global abort; every 1024 iters check abort. Returns nonzero on abort.
__device__ __forceinline__ int gate(const unsigned* locl, const unsigned* mir,
                                    unsigned tgt, int lane, unsigned* abf) {
    int it = 0;
    for (;;) {
        unsigned v = tgt;
        if (locl) { if (lane < 32) v = ld32_sc0(locl + lane); }
        else      { if (lane < 32) v = ald32(mir + lane); }
        if (__all((int)(v >= tgt))) return 0;
        ++it;
        if (locl && (it & 255) == 192) {          // fail-soft: mirror sample
            unsigned m = tgt;
            if (lane < 32) m = ald32(mir + lane);
            if (__all((int)(m >= tgt))) return 0;
        }
        if (it >= (1 << 20)) { ast32(abf, 1u); return 1; }
        if ((it & 1023) == 0 && ald32(abf) != 0u) return 1;
        __builtin_amdgcn_s_sleep(1);
    }
}

// One-shot canonicalization: fp32 weights -> bf16 ws copies; bias pre-sums; x transpose.
__global__ __launch_bounds__(256) void canon(
    const float* __restrict__ x,
    const float* __restrict__ Whh1, const float* __restrict__ Wih2,
    const float* __restrict__ Whh2, const float* __restrict__ Wlin,
    const float* __restrict__ bih1, const float* __restrict__ bhh1,
    const float* __restrict__ bih2, const float* __restrict__ bhh2,
    __hip_bfloat16* __restrict__ Whh1c, __hip_bfloat16* __restrict__ Wih2c,
    __hip_bfloat16* __restrict__ Whh2c, __hip_bfloat16* __restrict__ Wlinc,
    float* __restrict__ bsum1, float* __restrict__ bsum2,
    float* __restrict__ xT)
{
    const int tid = blockIdx.x * 256 + threadIdx.x;
    const int np  = gridDim.x * 256;
    for (int i = tid; i < 2048 * 512; i += np) {
        Whh1c[i] = __float2bfloat16(Whh1[i]);
        Wih2c[i] = __float2bfloat16(Wih2[i]);
        Whh2c[i] = __float2bfloat16(Whh2[i]);
    }
    for (int i = tid; i < 256 * 512; i += np) Wlinc[i] = __float2bfloat16(Wlin[i]);
    for (int i = tid; i < 2048; i += np) {
        bsum1[i] = bih1[i] + bhh1[i];
        bsum2[i] = bih2[i] + bhh2[i];
    }
    for (int i = tid; i < BB * TT; i += np) {
        int b = i >> 10, t = i & 1023;
        xT[t * BB + b] = x[i];
    }
}

// ---- stage loops (shared by PURE and FALLBACK via gate/publish pointers) ----

__device__ __forceinline__ void s1_loop(
    const float* __restrict__ xT, const __hip_bfloat16* lds,
    unsigned* gloc, unsigned* gmir,              // own-group gate (loc null in FB)
    unsigned* ploc, unsigned* pA, unsigned* pB,  // publish: local, mirrorA, mirrorB
    unsigned* abf, unsigned* h1all, unsigned* s_ab,
    const float* wv, const float* bs,
    int lane, int w, int lb, int ln,
    int aoff, int o0, int o1, int xoff, int rA)
{
    float cre[4] = {0.f, 0.f, 0.f, 0.f};
    const __hip_bfloat16* h1bf = (const __hip_bfloat16*)h1all;
    for (int t = 0; t < TT; ++t) {
        int ab = 0;
        floatx4 acc[4];
        #pragma unroll
        for (int g = 0; g < 4; ++g) acc[g] = floatx4{0, 0, 0, 0};
        unsigned pk[4];

        if (t > 0) ab = gate(gloc, gmir, (unsigned)t, lane, abf);
        cfence();
        if (!ab) {
            const __hip_bfloat16* hA = h1bf + (size_t)t * 65536;   // h1(t-1)
            float4 xv4 = *(const float4*)(xT + t * BB + xoff);
            short8 A0[16];
            #pragma unroll
            for (int kk = 0; kk < 16; ++kk)
                A0[kk] = *(const short8*)(hA + aoff + kk * 32);
            #pragma unroll
            for (int kk = 0; kk < 16; ++kk) {
                #pragma unroll
                for (int g = 0; g < 4; ++g)
                    acc[g] = mfma16(A0[kk],
                        *(const short8*)(lds + ((g * 16 + kk) * 64 + lane) * 8), acc[g]);
            }
            #pragma unroll
            for (int reg = 0; reg < 4; ++reg) {
                const float xv = ((const float*)&xv4)[reg];
                float gi = acc[0][reg] + xv * wv[0] + bs[0];
                float gf = acc[1][reg] + xv * wv[1] + bs[1];
                float gg = acc[2][reg] + xv * wv[2] + bs[2];
                float go = acc[3][reg] + xv * wv[3] + bs[3];
                float cn = sigm(gf) * cre[reg] + sigm(gi) * tanh_fast(gg);
                cre[reg] = cn;
                float hn = sigm(go) * tanh_fast(cn);
                __hip_bfloat16 hb = __float2bfloat16(hn);
                unsigned short us; __builtin_memcpy(&us, &hb, 2);
                unsigned mine = us;
                unsigned other = (unsigned)__shfl_xor((int)mine, 1, 64);
                pk[reg] = (ln & 1) ? ((other & 0xffffu) | (mine << 16))
                                   : ((mine & 0xffffu) | (other << 16));
            }
            unsigned* dst = h1all + (size_t)(t + 1) * 32768;   // h1(t) -> slot t+1
            ast32(dst + o0, pk[rA]);                           // MALL (cross-XCD读)
            ast32(dst + o1, pk[rA + 1]);
        }
        vmcnt0();
        if (lane == 0) s_ab[(t & 1) * 4 + w] = (unsigned)ab;
        __syncthreads();
        unsigned bab = s_ab[(t & 1) * 4] | s_ab[(t & 1) * 4 + 1]
                     | s_ab[(t & 1) * 4 + 2] | s_ab[(t & 1) * 4 + 3];
        if (threadIdx.x == 0 && !bab) {
            if (ploc) ploc[lb] = (unsigned)(t + 1);    // plain: local-L2 release
            ast32(pA + lb, (unsigned)(t + 1));         // MALL mirror / FB line
            if (pB) ast32(pB + lb, (unsigned)(t + 1)); // FB consumer copy
        }
        if (bab) return;
    }
}

template<int PURE>
__device__ __forceinline__ void s2_loop(
    const __hip_bfloat16* lds,
    unsigned* ffmir,                             // feed-forward gate (MALL)
    unsigned* rloc, unsigned* rmir,              // recurrence gate (loc null in FB)
    unsigned* ploc, unsigned* pA,
    unsigned* abf, unsigned* h1all, unsigned* h2ring, __hip_bfloat16* h2slots,
    unsigned* s_ab, const float* bs,
    int lane, int w, int lb, int ln,
    int aoff, int o0, int o1, int bA, int jc, int rA)
{
    float cre[4] = {0.f, 0.f, 0.f, 0.f};
    const __hip_bfloat16* h1bf = (const __hip_bfloat16*)h1all;
    for (int t = 0; t < TT; ++t) {
        int ab = 0;
        floatx4 acc[4];
        #pragma unroll
        for (int g = 0; g < 4; ++g) acc[g] = floatx4{0, 0, 0, 0};
        unsigned pk[4];

        // feed-forward: h1(t) durable (S1 runs ahead; usually stale-satisfied)
        ab = gate(nullptr, ffmir, (unsigned)(t + 1), lane, abf);
        cfence();
        if (!ab) {
            const __hip_bfloat16* hA = h1bf + (size_t)(t + 1) * 65536;
            short8 A0[16];
            #pragma unroll
            for (int kk = 0; kk < 16; ++kk)
                A0[kk] = *(const short8*)(hA + aoff + kk * 32);
            #pragma unroll
            for (int kk = 0; kk < 16; ++kk) {
                #pragma unroll
                for (int g = 0; g < 4; ++g)
                    acc[g] = mfma16(A0[kk],
                        *(const short8*)(lds + ((g * 16 + kk) * 64 + lane) * 8), acc[g]);
            }
        }
        // recurrence: h2(t-1)
        if (t > 0 && !ab) {
            ab = gate(rloc, rmir, (unsigned)t, lane, abf);
            cfence();
            if (!ab) {
                const __hip_bfloat16* hB =
                    (const __hip_bfloat16*)h2ring + (size_t)(t & 3) * 65536;
                short8 A1[16];
                #pragma unroll
                for (int kk = 0; kk < 16; ++kk)
                    A1[kk] = PURE ? ld16_sc0(hB + aoff + kk * 32)
                                  : ld16_sc1(hB + aoff + kk * 32);
                vm_fence();
                #pragma unroll
                for (int kk = 0; kk < 16; ++kk) {
                    #pragma unroll
                    for (int g = 0; g < 4; ++g)
                        acc[g] = mfma16(A1[kk],
                            *(const short8*)(lds + 32768 + ((g * 16 + kk) * 64 + lane) * 8), acc[g]);
                }
            }
        }
        if (!ab) {
            #pragma unroll
            for (int reg = 0; reg < 4; ++reg) {
                float gi = acc[0][reg] + bs[0];
                float gf = acc[1][reg] + bs[1];
                float gg = acc[2][reg] + bs[2];
                float go = acc[3][reg] + bs[3];
                float cn = sigm(gf) * cre[reg] + sigm(gi) * tanh_fast(gg);
                cre[reg] = cn;
                float hn = sigm(go) * tanh_fast(cn);
                __hip_bfloat16 hb = __float2bfloat16(hn);
                unsigned short us; __builtin_memcpy(&us, &hb, 2);
                unsigned mine = us;
                unsigned other = (unsigned)__shfl_xor((int)mine, 1, 64);
                pk[reg] = (ln & 1) ? ((other & 0xffffu) | (mine << 16))
                                   : ((mine & 0xffffu) | (other << 16));
            }
            unsigned* dst = h2ring + (size_t)((t + 1) & 3) * 32768;  // h2(t)
            if (PURE) {               // plain: stays dirty in own XCD's L2
                dst[o0] = pk[rA];
                dst[o1] = pk[rA + 1];
            } else {                  // MALL (proven FB path)
                ast32(dst + o0, pk[rA]);
                ast32(dst + o1, pk[rA + 1]);
            }
        }
        vmcnt0();
        if (lane == 0) s_ab[(t & 1) * 4 + w] = (unsigned)ab;
        __syncthreads();
        unsigned bab = s_ab[(t & 1) * 4] | s_ab[(t & 1) * 4 + 1]
                     | s_ab[(t & 1) * 4 + 2] | s_ab[(t & 1) * 4 + 3];
        if (threadIdx.x == 0 && !bab) {
            if (ploc) ploc[lb] = (unsigned)(t + 1);
            ast32(pA + lb, (unsigned)(t + 1));
        }
        if (!bab) {
            unsigned* outs = (unsigned*)h2slots;   // fire-and-forget output
            outs[(((size_t)bA * TT + t) * HH + jc) >> 1]       = pk[rA];
            outs[(((size_t)(bA + 1) * TT + t) * HH + jc) >> 1] = pk[rA + 1];
        }
        if (bab) return;
    }
}

// Persistent dataflow LSTM, XCD-localized with single-writer mode decision.
// flags layout (1024-word = 4KB lines):
//   0-3  loc lines (PURE): [s1h0, s1h1, s2h0, s2h1] — plain store + sc0 poll
//   4-7  mir lines (PURE): same order — agent, cross-XCD + fail-soft
//   8-9  FB line1 h0/h1; 10-11 FB line2 h0/h1; 12-13 FB line1c h0/h1
//   14   abort @word0, mode @word64
//   15   census: xcdpop[8] @word0, arrived @word64
__global__ __launch_bounds__(256, 1) void lstm_persist(
    const float* __restrict__ xT,
    const float* __restrict__ Wih1,
    const __hip_bfloat16* __restrict__ Whh1c,
    const float* __restrict__ bsum1,
    const __hip_bfloat16* __restrict__ Wih2c,
    const __hip_bfloat16* __restrict__ Whh2c,
    const float* __restrict__ bsum2,
    unsigned* __restrict__ flags,
    unsigned* __restrict__ h1all,              // [1025][B*H/2] u32
    unsigned* __restrict__ h2ring,             // [4][B*H/2] u32
    __hip_bfloat16* __restrict__ h2slots)      // d_out as bf16 slots [B][T][H]
{
    extern __shared__ __hip_bfloat16 lds[];
    __shared__ unsigned s_ab[8];
    __shared__ unsigned smeta;

    unsigned* abf     = flags + 14 * 1024;
    unsigned* modew   = flags + 14 * 1024 + 64;
    unsigned* xcdpop  = flags + 15 * 1024;
    unsigned* arrived = flags + 15 * 1024 + 64;

    // ---- census + single-writer mode decision (all spins watchdogged) ----
    if (threadIdx.x == 0) {
        const unsigned xcc  = get_xcc();
        const unsigned rank = atomicAdd(&xcdpop[xcc], 1u);
        atomicAdd(arrived, 1u);
        unsigned mode;
        if (blockIdx.x == 0) {
            int it = 0; unsigned got;
            for (;;) {
                got = ald32(arrived);
                if (got >= (unsigned)NBLK || ++it >= (1 << 15)) break;
                __builtin_amdgcn_s_sleep(8);
            }
            if (got >= (unsigned)NBLK) {
                int ok = 1;
                for (int i = 0; i < 8; ++i) ok &= (ald32(&xcdpop[i]) == 32u);
                mode = ok ? 1u : 2u;       // PURE iff honest 32-per-XCD census
            } else mode = 2u;              // residency shortfall -> FALLBACK
            ast32(modew, mode);
        }
        { int it = 0;
          while ((mode = ald32(modew)) == 0u) {
              if (++it >= (1 << 17)) { mode = 2u; break; }
              __builtin_amdgcn_s_sleep(8);
          } }
        smeta = (mode << 16) | ((xcc & 7u) << 8) | (rank & 255u);
    }
    __syncthreads();
    const unsigned mv   = smeta;
    const unsigned mode = mv >> 16;
    int stage, half, lb;
    bool active;
    if (mode == 1u) {                        // PURE: roles by XCD
        const unsigned xcc = (mv >> 8) & 7u, rank = mv & 255u;
        active = (xcc < 4u) && (rank < 32u);
        stage = (int)(xcc >> 1); half = (int)(xcc & 1u); lb = (int)rank;
    } else {                                 // FALLBACK: proven R6 roles
        active = (blockIdx.x < 128);
        stage = (int)(blockIdx.x >> 6);
        half  = (int)((blockIdx.x >> 5) & 1);
        lb    = (int)(blockIdx.x & 31);
    }
    if (!active) return;

    const int j0   = lb * 16;
    const int w    = threadIdx.x >> 6;
    const int lane = threadIdx.x & 63;
    const int q    = lane >> 4, ln = lane & 15;
    const int r0   = half * 64 + w * 16;

    // ---- stage weights into LDS, fragment-permuted (once) ----
    {
        const __hip_bfloat16* S0 = (stage == 0) ? Whh1c : Wih2c;
        for (int idx = threadIdx.x; idx < 4096; idx += 256) {
            const int g = idx >> 10, kk = (idx >> 6) & 15, l = idx & 63;
            const int lnt = l & 15, qt = l >> 4;
            const size_t src = (size_t)(g * 512 + j0 + lnt) * 512 + kk * 32 + qt * 8;
            *(float4*)(lds + idx * 8) = *(const float4*)(S0 + src);
            if (stage == 1)
                *(float4*)(lds + 32768 + idx * 8) = *(const float4*)(Whh2c + src);
        }
    }
    __syncthreads();

    float wv[4], bs[4];
    #pragma unroll
    for (int g = 0; g < 4; ++g) {
        const int j = g * 512 + j0 + ln;
        if (stage == 0) { wv[g] = Wih1[j]; bs[g] = bsum1[j]; }
        else            { wv[g] = 0.0f;    bs[g] = bsum2[j]; }
    }

    const int aoff = (r0 + ln) * HH + q * 8;
    const int jc   = j0 + (ln & ~1);
    const int rA   = (ln & 1) ? 2 : 0;
    const int bA   = r0 + q * 4 + rA;
    const int o0   = (bA * HH + jc) >> 1;
    const int o1   = ((bA + 1) * HH + jc) >> 1;
    const int xoff = r0 + q * 4;

    if (stage == 0) {
        unsigned *gloc, *gmir, *ploc, *pA, *pB;
        if (mode == 1u) {
            gloc = flags + (0 * 2 + half) * 1024;        // loc1
            gmir = flags + (4 + 0 * 2 + half) * 1024;    // mir1
            ploc = gloc; pA = gmir; pB = nullptr;
        } else {
            gloc = nullptr;
            gmir = flags + (8 + half) * 1024;            // FB line1
            ploc = nullptr; pA = gmir;
            pB   = flags + (12 + half) * 1024;           // FB line1c
        }
        s1_loop(xT, lds, gloc, gmir, ploc, pA, pB, abf, h1all, s_ab,
                wv, bs, lane, w, lb, ln, aoff, o0, o1, xoff, rA);
    } else {
        unsigned *ffmir, *rloc, *rmir, *ploc, *pA;
        if (mode == 1u) {
            ffmir = flags + (4 + 0 * 2 + half) * 1024;   // mir1 (cross-XCD edge)
            rloc  = flags + (1 * 2 + half) * 1024;       // loc2
            rmir  = flags + (4 + 1 * 2 + half) * 1024;   // mir2 (fail-soft only)
            ploc  = rloc; pA = rmir;
            s2_loop<1>(lds, ffmir, rloc, rmir, ploc, pA, abf, h1all, h2ring,
                       h2slots, s_ab, bs, lane, w, lb, ln, aoff, o0, o1, bA, jc, rA);
        } else {
            ffmir = flags + (12 + half) * 1024;          // FB line1c
            rloc  = nullptr;
            rmir  = flags + (10 + half) * 1024;          // FB line2
            ploc  = nullptr; pA = rmir;
            s2_loop<0>(lds, ffmir, rloc, rmir, ploc, pA, abf, h1all, h2ring,
                       h2slots, s_ab, bs, lane, w, lb, ln, aoff, o0, o1, bA, jc, rA);
        }
    }
}

// In-place linear+softmax over all T*B rows (slot r: 512 bf16 -> 256 fp32).
__global__ __launch_bounds__(256) void lin_softmax(
    const __hip_bfloat16* __restrict__ Wlinc,
    const float* __restrict__ blin,
    float* out)
{
    const __hip_bfloat16* slots = (const __hip_bfloat16*)out;
    const int w = threadIdx.x >> 6;
    const int lane = threadIdx.x & 63;
    const int q = lane >> 4, ln = lane & 15;
    const int r0 = blockIdx.x * 64 + w * 16;

    floatx4 acc[16];
    #pragma unroll
    for (int n = 0; n < 16; ++n) acc[n] = floatx4{0, 0, 0, 0};

    const size_t arow = (size_t)(r0 + ln) * HH + q * 8;
    #pragma unroll 4
    for (int kk = 0; kk < 16; ++kk) {
        short8 a = *(const short8*)(slots + arow + kk * 32);
        #pragma unroll
        for (int n = 0; n < 16; ++n) {
            short8 bf = *(const short8*)(Wlinc + (n * 16 + ln) * HH + kk * 32 + q * 8);
            acc[n] = mfma16(a, bf, acc[n]);
        }
    }

    float bl[16];
    #pragma unroll
    for (int n = 0; n < 16; ++n) bl[n] = blin[n * 16 + ln];

    #pragma unroll
    for (int reg = 0; reg < 4; ++reg) {
        float v[16];
        float mx = -3.4e38f;
        #pragma unroll
        for (int n = 0; n < 16; ++n) {
            v[n] = acc[n][reg] + bl[n];
            mx = fmaxf(mx, v[n]);
        }
        #pragma unroll
        for (int m = 1; m < 16; m <<= 1) mx = fmaxf(mx, __shfl_xor(mx, m));
        float sum = 0.0f;
        #pragma unroll
        for (int n = 0; n < 16; ++n) { v[n] = __expf(v[n] - mx); sum += v[n]; }
        #pragma unroll
        for (int m = 1; m < 16; m <<= 1) sum += __shfl_xor(sum, m);
        const float inv = 1.0f / sum;

        const int r = r0 + q * 4 + reg;        // r = b*T + t
        #pragma unroll
        for (int n = 0; n < 16; ++n)
            out[(size_t)r * VV + n * 16 + ln] = v[n] * inv;
    }
}

extern "C" void kernel_launch(void* const* d_in, const int* in_sizes, int n_in,
                              void* d_out, int out_size, void* d_ws, size_t ws_size,
                              hipStream_t stream)
{
    const float* x     = (const float*)d_in[0];
    const float* W_ih1 = (const float*)d_in[1];
    const float* W_hh1 = (const float*)d_in[2];
    const float* b_ih1 = (const float*)d_in[3];
    const float* b_hh1 = (const float*)d_in[4];
    const float* W_ih2 = (const float*)d_in[5];
    const float* W_hh2 = (const float*)d_in[6];
    const float* b_ih2 = (const float*)d_in[7];
    const float* b_hh2 = (const float*)d_in[8];
    const float* W_lin = (const float*)d_in[9];
    const float* b_lin = (const float*)d_in[10];

    char* p = (char*)d_ws;
    unsigned* flags  = (unsigned*)p;   p += 65536;                    // 16 x 4KB lines
    unsigned* h1all  = (unsigned*)p;   p += (size_t)1025 * 131072;    // 128.1 MB
    const size_t zbytes = 65536 + 131072;                             // flags + h1 slot 0
    unsigned* h2ring = (unsigned*)p;   p += (size_t)4 * 131072;       // 512 KB
    float* bsum1 = (float*)p;          p += 2048 * 4;
    float* bsum2 = (float*)p;          p += 2048 * 4;
    float* xT    = (float*)p;          p += (size_t)BB * TT * 4;
    __hip_bfloat16* Whh1c = (__hip_bfloat16*)p; p += (size_t)2048 * 512 * 2;
    __hip_bfloat16* Wih2c = (__hip_bfloat16*)p; p += (size_t)2048 * 512 * 2;
    __hip_bfloat16* Whh2c = (__hip_bfloat16*)p; p += (size_t)2048 * 512 * 2;
    __hip_bfloat16* Wlinc = (__hip_bfloat16*)p; p += (size_t)256 * 512 * 2;
    // total ws use ~142 MB (proven available)

    hipMemsetAsync(d_ws, 0, zbytes, stream);   // flags/census/abort + h1 slot 0

    canon<<<dim3(512), dim3(256), 0, stream>>>(
        x, W_hh1, W_ih2, W_hh2, W_lin, b_ih1, b_hh1, b_ih2, b_hh2,
        Whh1c, Wih2c, Whh2c, Wlinc, bsum1, bsum2, xT);

    const int smem_bytes = 131072;   // 128 KB dynamic LDS => 1 block/CU
    (void)hipFuncSetAttribute((const void*)lstm_persist,
                              hipFuncAttributeMaxDynamicSharedMemorySize, smem_bytes);

    lstm_persist<<<dim3(NBLK), dim3(256), smem_bytes, stream>>>(
        xT, W_ih1, Whh1c, bsum1, Wih2c, Whh2c, bsum2,
        flags, h1all, h2ring, (__hip_bfloat16*)d_out);

    lin_softmax<<<dim3((TT * BB) / 64), dim3(256), 0, stream>>>(
        Wlinc, b_lin, (float*)d_out);
}